// Round 6
// baseline (112.356 us; speedup 1.0000x reference)
//
#include <hip/hip_runtime.h>
#include <hip/hip_bf16.h>

#define TWO_N  8192
#define N_HALF 4096
#define DIMS   256

typedef __bf16 bf16x8 __attribute__((ext_vector_type(8)));
typedef float  f32x4  __attribute__((ext_vector_type(4)));
typedef unsigned short ushort8v __attribute__((ext_vector_type(8)));

// raw v_exp_f32 (args here are bounded |x| <= ~3, no denormal/range handling needed)
__device__ __forceinline__ float fast_exp2(float x) {
#if __has_builtin(__builtin_amdgcn_exp2f)
    return __builtin_amdgcn_exp2f(x);
#else
    float r; asm("v_exp_f32 %0, %1" : "=v"(r) : "v"(x)); return r;
#endif
}

// async global->LDS, 16B per lane: LDS dest = wave-uniform base (HW adds
// lane*16), global src = per-lane pointer (guide §5; m97 pattern).
#define GLOAD_LDS16(g, l)                                                      \
    __builtin_amdgcn_global_load_lds(                                          \
        (const __attribute__((address_space(1))) unsigned int*)(g),            \
        (__attribute__((address_space(3))) unsigned int*)(l), 16, 0, 0)

// ---------------------------------------------------------------------------
// Kernel 1: normalize rows of reps = cat([zjs, zis]), pre-scale by
// sqrt(2*log2(e)) so MFMA dot = (1/TEMP)*log2(e)*sim, and store in MFMA
// fragment-swizzled order: chunk = ((row/16)*8 + kk)*64 + quad*16 + (row%16),
// each chunk = 8 bf16 = elements k in [quad*8 + kk*32, +8) of that row.
// One 32-lane half-wave per row (8 rows / 256-thread block).
// ---------------------------------------------------------------------------
__global__ __launch_bounds__(256) void nrm_kernel(const float* __restrict__ zis,
                                                  const float* __restrict__ zjs,
                                                  unsigned short* __restrict__ swz)
{
    const int tid = threadIdx.x;
    const int l32 = tid & 31;
    const int row = blockIdx.x * 8 + (tid >> 5);
    const int k0  = l32 * 8;

    const float* src = (row < N_HALF) ? (zjs + (size_t)row * DIMS)
                                      : (zis + (size_t)(row - N_HALF) * DIMS);
    const float4 v0 = reinterpret_cast<const float4*>(src + k0)[0];
    const float4 v1 = reinterpret_cast<const float4*>(src + k0 + 4)[0];
    float ss = v0.x * v0.x + v0.y * v0.y + v0.z * v0.z + v0.w * v0.w
             + v1.x * v1.x + v1.y * v1.y + v1.z * v1.z + v1.w * v1.w;
#pragma unroll
    for (int m = 1; m < 32; m <<= 1) ss += __shfl_xor(ss, m, 64);
    // norms ~16 for N(0,1) rows; cosine eps path can never trigger
    const float inv = rsqrtf(ss) * 1.69864360045f;  // * sqrt(2*log2(e))

    const float vals[8] = {v0.x, v0.y, v0.z, v0.w, v1.x, v1.y, v1.z, v1.w};
    ushort8v o;
#pragma unroll
    for (int j = 0; j < 8; ++j) {
        __hip_bfloat16 b = __float2bfloat16(vals[j] * inv);
        o[j] = *reinterpret_cast<unsigned short*>(&b);
    }
    // kk = k0>>5 = l32>>2, quad = l32&3
    const int chunk = ((row >> 4) * 8 + (l32 >> 2)) * 64 + (l32 & 3) * 16 + (row & 15);
    *reinterpret_cast<ushort8v*>(swz + (size_t)chunk * 8) = o;
}

// ---------------------------------------------------------------------------
// Kernel 2 (LDS-resident A, barrier-free loop): fused scaled-Gram (bf16 MFMA)
// + exp2 row partial sums + diag mask + positive extraction.
// R5 counters: MfmaUtil 28 / VALUBusy 22 / Occ 36 -> latency-bound on the
// per-iteration A-fragment L2/L3 loads (~220+ cy). Fix: K=256 means a block's
// whole A-panel (128 cols x 256 K = 64 KB) fits in LDS. Stage it ONCE per
// block (16x global_load_lds w16 per thread), one vmcnt(0)+barrier, then the
// main loop is pure {ds_read_b128, MFMA, exp} -- no global loads, no
// barriers, no vmcnt (avoids R4's per-iteration 2-phase stall entirely).
// Tile 256 rows x 128 cols, 4 waves (64 rows each), 2 blocks/CU (64 KB LDS),
// R0-style register double-buffer of a[8] from LDS for ILP.
// Grid 2048: blockIdx&31 -> row group (256 rows), blockIdx>>5 -> col chunk
// (128 cols). Math is bit-identical to round 0.
// ---------------------------------------------------------------------------
__global__ __launch_bounds__(256, 2) void ntx_kernel(const __bf16* __restrict__ swz,
                                                     float* __restrict__ rowsum_part,
                                                     float* __restrict__ pos_part)
{
    __shared__ __bf16 abuf[32768];   // 64 KB: 8 col-groups x 4096 (swz layout)

    const int lane = threadIdx.x & 63;
    const int wave = threadIdx.x >> 6;
    const int l15  = lane & 15;
    const int quad = lane >> 4;

    const int rg     = blockIdx.x & 31;
    const int cs     = blockIdx.x >> 5;       // 64 col chunks of 128
    const int wr0    = rg * 256 + wave * 64;
    const int c_base = cs * 128;
    const int p0     = wr0 ^ N_HALF;          // partner-row block (positives)

    // Stage the block's full A-panel: contiguous 64 KB region of swz
    // (col-groups cs*8 .. cs*8+7). Each wave covers a 16 KB quarter.
    {
        const __bf16* gsrc = swz + (size_t)cs * 32768 + wave * 8192 + lane * 8;
#pragma unroll
        for (int h = 0; h < 16; ++h)
            GLOAD_LDS16(gsrc + h * 512, &abuf[wave * 8192 + h * 512]);
    }

    // Hoist B (row) fragments: 4 groups of 16 rows, 8 K-chunks each.
    bf16x8 bfrag[4][8];
#pragma unroll
    for (int t = 0; t < 4; ++t) {
        const __bf16* bp = swz + (size_t)((wr0 >> 4) + t) * 4096 + lane * 8;
#pragma unroll
        for (int kk = 0; kk < 8; ++kk)
            bfrag[t][kk] = *reinterpret_cast<const bf16x8*>(bp + kk * 512);
    }

    float sum_exp[4] = {0.f, 0.f, 0.f, 0.f};
    float pos_acc = 0.f;

    asm volatile("s_waitcnt vmcnt(0)" ::: "memory");
    __syncthreads();   // A-panel resident; no further barriers needed

    auto compute = [&](const bf16x8* af, int it) {
        const int c0 = c_base + it * 16;
        f32x4 acc[4] = {{0.f, 0.f, 0.f, 0.f}, {0.f, 0.f, 0.f, 0.f},
                        {0.f, 0.f, 0.f, 0.f}, {0.f, 0.f, 0.f, 0.f}};
#pragma unroll
        for (int kk = 0; kk < 8; ++kk) {
#pragma unroll
            for (int t = 0; t < 4; ++t)
                acc[t] = __builtin_amdgcn_mfma_f32_16x16x32_bf16(
                    af[kk], bfrag[t][kk], acc[t], 0, 0, 0);
        }
        // acc = (1/TEMP)*log2(e)*sim ; D[m=row l15][n-> col quad*4+j]
        const bool special = (c0 < wr0 + 64 && c0 + 16 > wr0) ||
                             (c0 < p0 + 64 && c0 + 16 > p0);
        if (!special) {
#pragma unroll
            for (int t = 0; t < 4; ++t)
#pragma unroll
                for (int j = 0; j < 4; ++j)
                    sum_exp[t] += fast_exp2(acc[t][j]);
        } else {
#pragma unroll
            for (int t = 0; t < 4; ++t) {
                const int r = wr0 + t * 16 + l15;
#pragma unroll
                for (int j = 0; j < 4; ++j) {
                    const int c = c0 + quad * 4 + j;
                    const float e = fast_exp2(acc[t][j]);
                    sum_exp[t] += (c == r) ? 0.f : e;               // self-diag mask
                    if (c == (r ^ N_HALF)) pos_acc += acc[t][j];    // positive (scaled dot)
                }
            }
        }
    };

    bf16x8 a0[8], a1[8];
#pragma unroll
    for (int kk = 0; kk < 8; ++kk)
        a0[kk] = *reinterpret_cast<const bf16x8*>(&abuf[kk * 512 + lane * 8]);

    for (int it = 0; it < 8; it += 2) {
#pragma unroll
        for (int kk = 0; kk < 8; ++kk)
            a1[kk] = *reinterpret_cast<const bf16x8*>(&abuf[(it + 1) * 4096 + kk * 512 + lane * 8]);
        compute(a0, it);
        if (it + 2 < 8) {
#pragma unroll
            for (int kk = 0; kk < 8; ++kk)
                a0[kk] = *reinterpret_cast<const bf16x8*>(&abuf[(it + 2) * 4096 + kk * 512 + lane * 8]);
        }
        compute(a1, it + 1);
    }

    // Per-row partial: reduce over the 4 quads (col groups), one store per row.
#pragma unroll
    for (int t = 0; t < 4; ++t) {
        float s = sum_exp[t];
        s += __shfl_xor(s, 16, 64);
        s += __shfl_xor(s, 32, 64);
        if (lane < 16)
            rowsum_part[(size_t)cs * TWO_N + wr0 + t * 16 + lane] = s;
    }

    // Positive partial: every wave writes its slot (0 if no partner overlap).
#pragma unroll
    for (int m = 1; m < 64; m <<= 1) pos_acc += __shfl_xor(pos_acc, m, 64);
    if (lane == 0) pos_part[blockIdx.x * 4 + wave] = pos_acc;
}

// ---------------------------------------------------------------------------
// Kernel 3: per-row ln(sum of 64 partials), minus ln2 * positive partials
// (8192 pos slots = one per thread; slot->row mapping irrelevant for the
// global sum). 8 blocks x 1024 threads, coalesced reads.
// ---------------------------------------------------------------------------
__global__ __launch_bounds__(1024) void fin1_kernel(const float* __restrict__ rowsum_part,
                                                    const float* __restrict__ pos_part,
                                                    float* __restrict__ block_part)
{
    __shared__ float red[16];
    const int t = threadIdx.x;
    const int r = blockIdx.x * 1024 + t;
    float acc = 0.f;
#pragma unroll
    for (int cs = 0; cs < 64; ++cs)
        acc += rowsum_part[(size_t)cs * TWO_N + r];
    float v = logf(acc) - 0.69314718055994531f * pos_part[r];
#pragma unroll
    for (int m = 1; m < 64; m <<= 1) v += __shfl_xor(v, m, 64);
    if ((t & 63) == 0) red[t >> 6] = v;
    __syncthreads();
    if (t == 0) {
        float s = 0.f;
#pragma unroll
        for (int w = 0; w < 16; ++w) s += red[w];
        block_part[blockIdx.x] = s;
    }
}

// ---------------------------------------------------------------------------
// Kernel 4: final scalar.
// ---------------------------------------------------------------------------
__global__ void fin2_kernel(const float* __restrict__ block_part, float* __restrict__ out)
{
    if (threadIdx.x == 0) {
        float s = 0.f;
#pragma unroll
        for (int i = 0; i < 8; ++i) s += block_part[i];
        out[0] = s / (float)TWO_N;
    }
}

// ---------------------------------------------------------------------------
extern "C" void kernel_launch(void* const* d_in, const int* in_sizes, int n_in,
                              void* d_out, int out_size, void* d_ws, size_t ws_size,
                              hipStream_t stream)
{
    const float* zis = (const float*)d_in[0];
    const float* zjs = (const float*)d_in[1];

    // ws: [0,4MB) swizzled bf16; [4MB,+2MB) rowsum partials [64][8192];
    //     then pos partials [8192]; then block partials [8].
    unsigned short* swz = (unsigned short*)d_ws;
    float* rowsum_part  = (float*)((char*)d_ws + (size_t)TWO_N * DIMS * sizeof(unsigned short));
    float* pos_part     = rowsum_part + (size_t)64 * TWO_N;
    float* block_part   = pos_part + TWO_N;

    nrm_kernel<<<TWO_N / 8, 256, 0, stream>>>(zis, zjs, swz);
    ntx_kernel<<<2048, 256, 0, stream>>>((const __bf16*)swz, rowsum_part, pos_part);
    fin1_kernel<<<8, 1024, 0, stream>>>(rowsum_part, pos_part, block_part);
    fin2_kernel<<<1, 64, 0, stream>>>(block_part, (float*)d_out);
}

// Round 7
// 92.090 us; speedup vs baseline: 1.2201x; 1.2201x over previous
//
#include <hip/hip_runtime.h>
#include <hip/hip_bf16.h>

#define TWO_N  8192
#define N_HALF 4096
#define DIMS   256

typedef __bf16 bf16x8 __attribute__((ext_vector_type(8)));
typedef float  f32x4  __attribute__((ext_vector_type(4)));
typedef unsigned short ushort8v __attribute__((ext_vector_type(8)));

// raw v_exp_f32 (args here are bounded |x| <= ~3, no denormal/range handling needed)
__device__ __forceinline__ float fast_exp2(float x) {
#if __has_builtin(__builtin_amdgcn_exp2f)
    return __builtin_amdgcn_exp2f(x);
#else
    float r; asm("v_exp_f32 %0, %1" : "=v"(r) : "v"(x)); return r;
#endif
}

// async global->LDS, 16B per lane: LDS dest = wave-uniform base (HW adds
// lane*16), global src = per-lane pointer (guide §5; m97 pattern).
#define GLOAD_LDS16(g, l)                                                      \
    __builtin_amdgcn_global_load_lds(                                          \
        (const __attribute__((address_space(1))) unsigned int*)(g),            \
        (__attribute__((address_space(3))) unsigned int*)(l), 16, 0, 0)

// ---------------------------------------------------------------------------
// Kernel 1: normalize rows of reps = cat([zjs, zis]), pre-scale by
// sqrt(2*log2(e)) so MFMA dot = (1/TEMP)*log2(e)*sim, and store in MFMA
// fragment-swizzled order: chunk = ((row/16)*8 + kk)*64 + quad*16 + (row%16),
// each chunk = 8 bf16 = elements k in [quad*8 + kk*32, +8) of that row.
// One 32-lane half-wave per row (8 rows / 256-thread block).
// ---------------------------------------------------------------------------
__global__ __launch_bounds__(256) void nrm_kernel(const float* __restrict__ zis,
                                                  const float* __restrict__ zjs,
                                                  unsigned short* __restrict__ swz)
{
    const int tid = threadIdx.x;
    const int l32 = tid & 31;
    const int row = blockIdx.x * 8 + (tid >> 5);
    const int k0  = l32 * 8;

    const float* src = (row < N_HALF) ? (zjs + (size_t)row * DIMS)
                                      : (zis + (size_t)(row - N_HALF) * DIMS);
    const float4 v0 = reinterpret_cast<const float4*>(src + k0)[0];
    const float4 v1 = reinterpret_cast<const float4*>(src + k0 + 4)[0];
    float ss = v0.x * v0.x + v0.y * v0.y + v0.z * v0.z + v0.w * v0.w
             + v1.x * v1.x + v1.y * v1.y + v1.z * v1.z + v1.w * v1.w;
#pragma unroll
    for (int m = 1; m < 32; m <<= 1) ss += __shfl_xor(ss, m, 64);
    // norms ~16 for N(0,1) rows; cosine eps path can never trigger
    const float inv = rsqrtf(ss) * 1.69864360045f;  // * sqrt(2*log2(e))

    const float vals[8] = {v0.x, v0.y, v0.z, v0.w, v1.x, v1.y, v1.z, v1.w};
    ushort8v o;
#pragma unroll
    for (int j = 0; j < 8; ++j) {
        __hip_bfloat16 b = __float2bfloat16(vals[j] * inv);
        o[j] = *reinterpret_cast<unsigned short*>(&b);
    }
    // kk = k0>>5 = l32>>2, quad = l32&3
    const int chunk = ((row >> 4) * 8 + (l32 >> 2)) * 64 + (l32 & 3) * 16 + (row & 15);
    *reinterpret_cast<ushort8v*>(swz + (size_t)chunk * 8) = o;
}

// ---------------------------------------------------------------------------
// Kernel 2 (512x512 tile, 1 block/CU, chunked LDS A): fused scaled-Gram
// (bf16 MFMA) + exp2 row partial sums + diag mask + positive extraction.
// Model from R0-R6 evidence: R0's per-wave A-streams = 640 MB of L2 traffic
// in ~40us = ~4.3 TB/s per XCD = L2 BW SATURATED (the real limiter; R4/R6
// proved traffic cuts work only if barriers stay rare and prologue is paid
// once). Here: grid 256 = 1 block/CU (prologue once, zero tail), 8 waves,
// 512x512 tile. A processed in 4 chunks of 128 cols; each 64 KB chunk staged
// into LDS ONCE for all 8 waves (8x global_load_lds w16 per wave), double
// buffered; stage for chunk c+1 issues at chunk top, ONE vmcnt(0)+barrier per
// chunk (~2500 cyc period -> drain amortized, unlike R4's per-iteration one).
// L2 traffic: (256KB A + 256KB B)/block x 256 = 134 MB, ~5x below R0.
// Inner math bit-identical to R0 (same fragments, same left-to-right col
// accumulation per row; rowsum slot = 512-col group).
// ---------------------------------------------------------------------------
__global__ __launch_bounds__(512, 2) void ntx_kernel(const __bf16* __restrict__ swz,
                                                     float* __restrict__ rowsum_part,
                                                     float* __restrict__ pos_part)
{
    __shared__ __bf16 abuf[2][32768];   // 2 x 64 KB (chunk double-buffer)

    const int lane = threadIdx.x & 63;
    const int wave = threadIdx.x >> 6;   // 0..7
    const int l15  = lane & 15;
    const int quad = lane >> 4;

    const int rg     = blockIdx.x & 15;   // 16 row groups of 512
    const int cs     = blockIdx.x >> 4;   // 16 col groups of 512
    const int wr0    = rg * 512 + wave * 64;
    const int p0     = wr0 ^ N_HALF;      // partner-row window (positives)

    // stage chunk c (128 cols = 8 col-16-groups) into abuf[buf]:
    // wave w covers group w (4096 elems = 8 KB) as 8 x 1KB wave-issues.
    auto stage = [&](int buf, int c) {
        const __bf16* gsrc = swz + (size_t)(cs * 32 + c * 8 + wave) * 4096 + lane * 8;
#pragma unroll
        for (int h = 0; h < 8; ++h)
            GLOAD_LDS16(gsrc + h * 512, &abuf[buf][wave * 4096 + h * 512]);
    };

    stage(0, 0);   // chunk 0 in flight while B fragments load

    // Hoist B (row) fragments: 4 groups of 16 rows, 8 K-chunks each (128 VGPR).
    bf16x8 bfrag[4][8];
#pragma unroll
    for (int t = 0; t < 4; ++t) {
        const __bf16* bp = swz + (size_t)((wr0 >> 4) + t) * 4096 + lane * 8;
#pragma unroll
        for (int kk = 0; kk < 8; ++kk)
            bfrag[t][kk] = *reinterpret_cast<const bf16x8*>(bp + kk * 512);
    }

    float sum_exp[4] = {0.f, 0.f, 0.f, 0.f};
    float pos_acc = 0.f;

    asm volatile("s_waitcnt vmcnt(0)" ::: "memory");
    __syncthreads();   // chunk 0 resident

    int cur = 0;
    for (int c = 0; c < 4; ++c) {
        if (c < 3) stage(cur ^ 1, c + 1);   // prefetch next chunk (counted later)

        const int cc_base = cs * 512 + c * 128;

        auto compute = [&](const bf16x8* af, int it) {
            const int c0 = cc_base + it * 16;
            f32x4 acc[4] = {{0.f, 0.f, 0.f, 0.f}, {0.f, 0.f, 0.f, 0.f},
                            {0.f, 0.f, 0.f, 0.f}, {0.f, 0.f, 0.f, 0.f}};
#pragma unroll
            for (int kk = 0; kk < 8; ++kk) {
#pragma unroll
                for (int t = 0; t < 4; ++t)
                    acc[t] = __builtin_amdgcn_mfma_f32_16x16x32_bf16(
                        af[kk], bfrag[t][kk], acc[t], 0, 0, 0);
            }
            // acc = (1/TEMP)*log2(e)*sim ; D[m=row l15][n-> col quad*4+j]
            const bool special = (c0 < wr0 + 64 && c0 + 16 > wr0) ||
                                 (c0 < p0 + 64 && c0 + 16 > p0);
            if (!special) {
#pragma unroll
                for (int t = 0; t < 4; ++t)
#pragma unroll
                    for (int j = 0; j < 4; ++j)
                        sum_exp[t] += fast_exp2(acc[t][j]);
            } else {
#pragma unroll
                for (int t = 0; t < 4; ++t) {
                    const int r = wr0 + t * 16 + l15;
#pragma unroll
                    for (int j = 0; j < 4; ++j) {
                        const int col = c0 + quad * 4 + j;
                        const float e = fast_exp2(acc[t][j]);
                        sum_exp[t] += (col == r) ? 0.f : e;               // self-diag mask
                        if (col == (r ^ N_HALF)) pos_acc += acc[t][j];    // positive
                    }
                }
            }
        };

        // 8 sub-iterations (16 cols each) from LDS, register double-buffered.
        bf16x8 a0[8], a1[8];
#pragma unroll
        for (int kk = 0; kk < 8; ++kk)
            a0[kk] = *reinterpret_cast<const bf16x8*>(&abuf[cur][kk * 512 + lane * 8]);

        for (int it = 0; it < 8; it += 2) {
#pragma unroll
            for (int kk = 0; kk < 8; ++kk)
                a1[kk] = *reinterpret_cast<const bf16x8*>(
                    &abuf[cur][(it + 1) * 4096 + kk * 512 + lane * 8]);
            compute(a0, it);
            if (it + 2 < 8) {
#pragma unroll
                for (int kk = 0; kk < 8; ++kk)
                    a0[kk] = *reinterpret_cast<const bf16x8*>(
                        &abuf[cur][(it + 2) * 4096 + kk * 512 + lane * 8]);
            }
            compute(a1, it + 1);
        }

        // next chunk's stage was issued ~2500 cyc ago -> drain is ~free.
        asm volatile("s_waitcnt vmcnt(0)" ::: "memory");
        __syncthreads();
        cur ^= 1;
    }

    // Per-row partial: reduce over the 4 quads (col groups), one store per row.
#pragma unroll
    for (int t = 0; t < 4; ++t) {
        float s = sum_exp[t];
        s += __shfl_xor(s, 16, 64);
        s += __shfl_xor(s, 32, 64);
        if (lane < 16)
            rowsum_part[(size_t)cs * TWO_N + wr0 + t * 16 + lane] = s;
    }

    // Positive partial: every wave writes its slot (0 if no partner overlap).
#pragma unroll
    for (int m = 1; m < 64; m <<= 1) pos_acc += __shfl_xor(pos_acc, m, 64);
    if (lane == 0) pos_part[blockIdx.x * 8 + wave] = pos_acc;
}

// ---------------------------------------------------------------------------
// Kernel 3: per-row ln(sum of 16 partials), minus ln2 * positive partials
// (2048 pos slots; slot->row mapping irrelevant for the global sum).
// 8 blocks x 1024 threads, coalesced reads.
// ---------------------------------------------------------------------------
__global__ __launch_bounds__(1024) void fin1_kernel(const float* __restrict__ rowsum_part,
                                                    const float* __restrict__ pos_part,
                                                    float* __restrict__ block_part)
{
    __shared__ float red[16];
    const int t = threadIdx.x;
    const int r = blockIdx.x * 1024 + t;
    float acc = 0.f;
#pragma unroll
    for (int cs = 0; cs < 16; ++cs)
        acc += rowsum_part[(size_t)cs * TWO_N + r];
    float v = logf(acc);
    if (r < 2048)
        v -= 0.69314718055994531f * pos_part[r];
#pragma unroll
    for (int m = 1; m < 64; m <<= 1) v += __shfl_xor(v, m, 64);
    if ((t & 63) == 0) red[t >> 6] = v;
    __syncthreads();
    if (t == 0) {
        float s = 0.f;
#pragma unroll
        for (int w = 0; w < 16; ++w) s += red[w];
        block_part[blockIdx.x] = s;
    }
}

// ---------------------------------------------------------------------------
// Kernel 4: final scalar.
// ---------------------------------------------------------------------------
__global__ void fin2_kernel(const float* __restrict__ block_part, float* __restrict__ out)
{
    if (threadIdx.x == 0) {
        float s = 0.f;
#pragma unroll
        for (int i = 0; i < 8; ++i) s += block_part[i];
        out[0] = s / (float)TWO_N;
    }
}

// ---------------------------------------------------------------------------
extern "C" void kernel_launch(void* const* d_in, const int* in_sizes, int n_in,
                              void* d_out, int out_size, void* d_ws, size_t ws_size,
                              hipStream_t stream)
{
    const float* zis = (const float*)d_in[0];
    const float* zjs = (const float*)d_in[1];

    // ws: [0,4MB) swizzled bf16; then rowsum partials [16][8192] f32 (512KB);
    //     then pos partials [2048]; then block partials [8].
    unsigned short* swz = (unsigned short*)d_ws;
    float* rowsum_part  = (float*)((char*)d_ws + (size_t)TWO_N * DIMS * sizeof(unsigned short));
    float* pos_part     = rowsum_part + (size_t)16 * TWO_N;
    float* block_part   = pos_part + 2048;

    nrm_kernel<<<TWO_N / 8, 256, 0, stream>>>(zis, zjs, swz);
    ntx_kernel<<<256, 512, 0, stream>>>((const __bf16*)swz, rowsum_part, pos_part);
    fin1_kernel<<<8, 1024, 0, stream>>>(rowsum_part, pos_part, block_part);
    fin2_kernel<<<1, 64, 0, stream>>>(block_part, (float*)d_out);
}

// Round 8
// 91.891 us; speedup vs baseline: 1.2227x; 1.0022x over previous
//
#include <hip/hip_runtime.h>
#include <hip/hip_bf16.h>

#define TWO_N  8192
#define N_HALF 4096
#define DIMS   256

typedef __bf16 bf16x8 __attribute__((ext_vector_type(8)));
typedef float  f32x4  __attribute__((ext_vector_type(4)));
typedef unsigned short ushort8v __attribute__((ext_vector_type(8)));

// raw v_exp_f32 (args here are bounded |x| <= ~3, no denormal/range handling needed)
__device__ __forceinline__ float fast_exp2(float x) {
#if __has_builtin(__builtin_amdgcn_exp2f)
    return __builtin_amdgcn_exp2f(x);
#else
    float r; asm("v_exp_f32 %0, %1" : "=v"(r) : "v"(x)); return r;
#endif
}

// async global->LDS, 16B per lane: LDS dest = wave-uniform base (HW adds
// lane*16), global src = per-lane pointer (guide §5; m97 pattern).
#define GLOAD_LDS16(g, l)                                                      \
    __builtin_amdgcn_global_load_lds(                                          \
        (const __attribute__((address_space(1))) unsigned int*)(g),            \
        (__attribute__((address_space(3))) unsigned int*)(l), 16, 0, 0)

// ---------------------------------------------------------------------------
// Kernel 1: normalize rows of reps = cat([zjs, zis]), pre-scale by
// sqrt(2*log2(e)) so MFMA dot = (1/TEMP)*log2(e)*sim, and store in MFMA
// fragment-swizzled order: chunk = ((row/16)*8 + kk)*64 + quad*16 + (row%16),
// each chunk = 8 bf16 = elements k in [quad*8 + kk*32, +8) of that row.
// One 32-lane half-wave per row (8 rows / 256-thread block).
// ---------------------------------------------------------------------------
__global__ __launch_bounds__(256) void nrm_kernel(const float* __restrict__ zis,
                                                  const float* __restrict__ zjs,
                                                  unsigned short* __restrict__ swz)
{
    const int tid = threadIdx.x;
    const int l32 = tid & 31;
    const int row = blockIdx.x * 8 + (tid >> 5);
    const int k0  = l32 * 8;

    const float* src = (row < N_HALF) ? (zjs + (size_t)row * DIMS)
                                      : (zis + (size_t)(row - N_HALF) * DIMS);
    const float4 v0 = reinterpret_cast<const float4*>(src + k0)[0];
    const float4 v1 = reinterpret_cast<const float4*>(src + k0 + 4)[0];
    float ss = v0.x * v0.x + v0.y * v0.y + v0.z * v0.z + v0.w * v0.w
             + v1.x * v1.x + v1.y * v1.y + v1.z * v1.z + v1.w * v1.w;
#pragma unroll
    for (int m = 1; m < 32; m <<= 1) ss += __shfl_xor(ss, m, 64);
    // norms ~16 for N(0,1) rows; cosine eps path can never trigger
    const float inv = rsqrtf(ss) * 1.69864360045f;  // * sqrt(2*log2(e))

    const float vals[8] = {v0.x, v0.y, v0.z, v0.w, v1.x, v1.y, v1.z, v1.w};
    ushort8v o;
#pragma unroll
    for (int j = 0; j < 8; ++j) {
        __hip_bfloat16 b = __float2bfloat16(vals[j] * inv);
        o[j] = *reinterpret_cast<unsigned short*>(&b);
    }
    // kk = k0>>5 = l32>>2, quad = l32&3
    const int chunk = ((row >> 4) * 8 + (l32 >> 2)) * 64 + (l32 & 3) * 16 + (row & 15);
    *reinterpret_cast<ushort8v*>(swz + (size_t)chunk * 8) = o;
}

// ---------------------------------------------------------------------------
// Kernel 2 (R7 structure + deferred-epilogue pipeline): 512x512 tile,
// 1 block/CU (grid 256), 8 waves, chunked LDS A (4 x 64KB, double-buffered),
// one vmcnt(0)+barrier per 128-col chunk.
// NEW vs R7: TWO accumulator sets (accE/accO). The exp2+sum "drain" of
// sub-it i-1 is issued in the SHADOW of sub-it i's 32-MFMA burst (drains
// depend only on completed accs, so the VALU work hides under MFMA pipe
// occupancy instead of serializing after it -- R7's ~45% MfmaUtil was both
// lockstep waves idling the matrix pipe during their correlated exp tails).
// Drain order stays strictly ascending sub-it -> per-row sums bit-identical.
// ---------------------------------------------------------------------------
__global__ __launch_bounds__(512, 2) void ntx_kernel(const __bf16* __restrict__ swz,
                                                     float* __restrict__ rowsum_part,
                                                     float* __restrict__ pos_part)
{
    __shared__ __bf16 abuf[2][32768];   // 2 x 64 KB (chunk double-buffer)

    const int lane = threadIdx.x & 63;
    const int wave = threadIdx.x >> 6;   // 0..7
    const int l15  = lane & 15;
    const int quad = lane >> 4;

    const int rg     = blockIdx.x & 15;   // 16 row groups of 512
    const int cs     = blockIdx.x >> 4;   // 16 col groups of 512
    const int wr0    = rg * 512 + wave * 64;
    const int p0     = wr0 ^ N_HALF;      // partner-row window (positives)

    // stage chunk c (128 cols = 8 col-16-groups) into abuf[buf]:
    // wave w covers group w (4096 elems = 8 KB) as 8 x 1KB wave-issues.
    auto stage = [&](int buf, int c) {
        const __bf16* gsrc = swz + (size_t)(cs * 32 + c * 8 + wave) * 4096 + lane * 8;
#pragma unroll
        for (int h = 0; h < 8; ++h)
            GLOAD_LDS16(gsrc + h * 512, &abuf[buf][wave * 4096 + h * 512]);
    };

    stage(0, 0);   // chunk 0 in flight while B fragments load

    // Hoist B (row) fragments: 4 groups of 16 rows, 8 K-chunks each (128 VGPR).
    bf16x8 bfrag[4][8];
#pragma unroll
    for (int t = 0; t < 4; ++t) {
        const __bf16* bp = swz + (size_t)((wr0 >> 4) + t) * 4096 + lane * 8;
#pragma unroll
        for (int kk = 0; kk < 8; ++kk)
            bfrag[t][kk] = *reinterpret_cast<const bf16x8*>(bp + kk * 512);
    }

    float sum_exp[4] = {0.f, 0.f, 0.f, 0.f};
    float pos_acc = 0.f;

    // 32-MFMA burst into a named acc set (re-inits the set).
    auto burst = [&](f32x4* acc, const bf16x8* af) {
#pragma unroll
        for (int t = 0; t < 4; ++t) acc[t] = f32x4{0.f, 0.f, 0.f, 0.f};
#pragma unroll
        for (int kk = 0; kk < 8; ++kk) {
#pragma unroll
            for (int t = 0; t < 4; ++t)
                acc[t] = __builtin_amdgcn_mfma_f32_16x16x32_bf16(
                    af[kk], bfrag[t][kk], acc[t], 0, 0, 0);
        }
    };

    // exp2 + row-sum + diag/positive handling for a completed acc set.
    auto drain = [&](const f32x4* acc, int c0) {
        const bool special = (c0 < wr0 + 64 && c0 + 16 > wr0) ||
                             (c0 < p0 + 64 && c0 + 16 > p0);
        if (!special) {
#pragma unroll
            for (int t = 0; t < 4; ++t)
#pragma unroll
                for (int j = 0; j < 4; ++j)
                    sum_exp[t] += fast_exp2(acc[t][j]);
        } else {
#pragma unroll
            for (int t = 0; t < 4; ++t) {
                const int r = wr0 + t * 16 + l15;
#pragma unroll
                for (int j = 0; j < 4; ++j) {
                    const int col = c0 + quad * 4 + j;
                    const float e = fast_exp2(acc[t][j]);
                    sum_exp[t] += (col == r) ? 0.f : e;               // self-diag mask
                    if (col == (r ^ N_HALF)) pos_acc += acc[t][j];    // positive
                }
            }
        }
    };

    asm volatile("s_waitcnt vmcnt(0)" ::: "memory");
    __syncthreads();   // chunk 0 resident

    f32x4 accE[4], accO[4];
    int pc0 = -1;      // pending accO drain column base (-1 = none)

    int cur = 0;
    for (int c = 0; c < 4; ++c) {
        if (c < 3) stage(cur ^ 1, c + 1);   // prefetch next chunk

        const int cc_base = cs * 512 + c * 128;

        bf16x8 a0[8], a1[8];
#pragma unroll
        for (int kk = 0; kk < 8; ++kk)
            a0[kk] = *reinterpret_cast<const bf16x8*>(&abuf[cur][kk * 512 + lane * 8]);

        for (int it = 0; it < 8; it += 2) {
#pragma unroll
            for (int kk = 0; kk < 8; ++kk)
                a1[kk] = *reinterpret_cast<const bf16x8*>(
                    &abuf[cur][(it + 1) * 4096 + kk * 512 + lane * 8]);

            burst(accE, a0);                       // sub-it `it` in flight
            if (pc0 >= 0) drain(accO, pc0);        // prev odd sub-it, shadowed

            if (it + 2 < 8) {
#pragma unroll
                for (int kk = 0; kk < 8; ++kk)
                    a0[kk] = *reinterpret_cast<const bf16x8*>(
                        &abuf[cur][(it + 2) * 4096 + kk * 512 + lane * 8]);
            }

            burst(accO, a1);                       // sub-it `it+1` in flight
            drain(accE, cc_base + it * 16);        // this even sub-it, shadowed
            pc0 = cc_base + (it + 1) * 16;
        }

        // next chunk's stage was issued a full chunk ago -> drain is ~free.
        asm volatile("s_waitcnt vmcnt(0)" ::: "memory");
        __syncthreads();
        cur ^= 1;
    }
    drain(accO, pc0);   // final pending sub-it

    // Per-row partial: reduce over the 4 quads (col groups), one store per row.
#pragma unroll
    for (int t = 0; t < 4; ++t) {
        float s = sum_exp[t];
        s += __shfl_xor(s, 16, 64);
        s += __shfl_xor(s, 32, 64);
        if (lane < 16)
            rowsum_part[(size_t)cs * TWO_N + wr0 + t * 16 + lane] = s;
    }

    // Positive partial: every wave writes its slot (0 if no partner overlap).
#pragma unroll
    for (int m = 1; m < 64; m <<= 1) pos_acc += __shfl_xor(pos_acc, m, 64);
    if (lane == 0) pos_part[blockIdx.x * 8 + wave] = pos_acc;
}

// ---------------------------------------------------------------------------
// Kernel 3: per-row ln(sum of 16 partials), minus ln2 * positive partials
// (2048 pos slots; slot->row mapping irrelevant for the global sum).
// 8 blocks x 1024 threads, coalesced reads.
// ---------------------------------------------------------------------------
__global__ __launch_bounds__(1024) void fin1_kernel(const float* __restrict__ rowsum_part,
                                                    const float* __restrict__ pos_part,
                                                    float* __restrict__ block_part)
{
    __shared__ float red[16];
    const int t = threadIdx.x;
    const int r = blockIdx.x * 1024 + t;
    float acc = 0.f;
#pragma unroll
    for (int cs = 0; cs < 16; ++cs)
        acc += rowsum_part[(size_t)cs * TWO_N + r];
    float v = logf(acc);
    if (r < 2048)
        v -= 0.69314718055994531f * pos_part[r];
#pragma unroll
    for (int m = 1; m < 64; m <<= 1) v += __shfl_xor(v, m, 64);
    if ((t & 63) == 0) red[t >> 6] = v;
    __syncthreads();
    if (t == 0) {
        float s = 0.f;
#pragma unroll
        for (int w = 0; w < 16; ++w) s += red[w];
        block_part[blockIdx.x] = s;
    }
}

// ---------------------------------------------------------------------------
// Kernel 4: final scalar.
// ---------------------------------------------------------------------------
__global__ void fin2_kernel(const float* __restrict__ block_part, float* __restrict__ out)
{
    if (threadIdx.x == 0) {
        float s = 0.f;
#pragma unroll
        for (int i = 0; i < 8; ++i) s += block_part[i];
        out[0] = s / (float)TWO_N;
    }
}

// ---------------------------------------------------------------------------
extern "C" void kernel_launch(void* const* d_in, const int* in_sizes, int n_in,
                              void* d_out, int out_size, void* d_ws, size_t ws_size,
                              hipStream_t stream)
{
    const float* zis = (const float*)d_in[0];
    const float* zjs = (const float*)d_in[1];

    // ws: [0,4MB) swizzled bf16; then rowsum partials [16][8192] f32 (512KB);
    //     then pos partials [2048]; then block partials [8].
    unsigned short* swz = (unsigned short*)d_ws;
    float* rowsum_part  = (float*)((char*)d_ws + (size_t)TWO_N * DIMS * sizeof(unsigned short));
    float* pos_part     = rowsum_part + (size_t)16 * TWO_N;
    float* block_part   = pos_part + 2048;

    nrm_kernel<<<TWO_N / 8, 256, 0, stream>>>(zis, zjs, swz);
    ntx_kernel<<<256, 512, 0, stream>>>((const __bf16*)swz, rowsum_part, pos_part);
    fin1_kernel<<<8, 1024, 0, stream>>>(rowsum_part, pos_part, block_part);
    fin2_kernel<<<1, 64, 0, stream>>>(block_part, (float*)d_out);
}